// Round 8
// baseline (18661.504 us; speedup 1.0000x reference)
//
#include <hip/hip_runtime.h>
#include <hip/hip_bf16.h>

#define SEQ   512
#define BATCH 128
#define VOCAB 30000
#define EDIM  256
#define HDIM  256
#define NT    9

// ---------------- K0b: detect mask storage dtype ----------------
__global__ void k_detect(const unsigned char* __restrict__ m, int* __restrict__ flag) {
    __shared__ int ok_sh;
    if (threadIdx.x == 0) ok_sh = 1;
    __syncthreads();
    int b = threadIdx.x;  // 128 threads, one row each
    const uint4* row = (const uint4*)(m + b * SEQ);
    int ok = 1, prev = 1;
    for (int i = 0; i < SEQ / 16; ++i) {
        uint4 v = row[i];
        unsigned w[4] = {v.x, v.y, v.z, v.w};
        #pragma unroll
        for (int wi = 0; wi < 4; ++wi) {
            #pragma unroll
            for (int j = 0; j < 4; ++j) {
                int byte = (w[wi] >> (8 * j)) & 255;
                if (byte > 1 || byte > prev) ok = 0;
                prev = byte;
            }
        }
    }
    if (!ok) atomicAnd(&ok_sh, 0);
    __syncthreads();
    if (threadIdx.x == 0) *flag = ok_sh;
}

// ---------------- K1: table[v][n] = embed[v] . Wcat[n] + bias[n] ----------------
__global__ __launch_bounds__(256) void k_table_gemm(
    const float* __restrict__ emb, const float* __restrict__ Wf,
    const float* __restrict__ Wb, const float* __restrict__ bf,
    const float* __restrict__ bb, float* __restrict__ table) {
    __shared__ __align__(16) float As[64][68];  // [k][m]
    __shared__ __align__(16) float Bs[64][68];  // [k][n]
    int t  = threadIdx.x;
    int tx = t & 15, ty = t >> 4;
    int n0 = blockIdx.x * 64;
    int v0 = blockIdx.y * 64;
    float acc[4][4] = {};
    for (int kc = 0; kc < 4; ++kc) {
        #pragma unroll
        for (int rr = 0; rr < 4; ++rr) {
            int slot = t + rr * 256;
            int m = slot >> 4, kq = slot & 15;
            int v = v0 + m;
            float4 a = (v < VOCAB)
                ? *(const float4*)&emb[v * EDIM + kc * 64 + kq * 4]
                : make_float4(0.f, 0.f, 0.f, 0.f);
            As[kq * 4 + 0][m] = a.x; As[kq * 4 + 1][m] = a.y;
            As[kq * 4 + 2][m] = a.z; As[kq * 4 + 3][m] = a.w;
            int n = n0 + m;
            const float* Wrow = (n < 1024) ? &Wf[n * 256] : &Wb[(n - 1024) * 256];
            float4 bvec = *(const float4*)&Wrow[kc * 64 + kq * 4];
            Bs[kq * 4 + 0][m] = bvec.x; Bs[kq * 4 + 1][m] = bvec.y;
            Bs[kq * 4 + 2][m] = bvec.z; Bs[kq * 4 + 3][m] = bvec.w;
        }
        __syncthreads();
        #pragma unroll
        for (int k = 0; k < 64; ++k) {
            float4 a = *(const float4*)&As[k][ty * 4];
            float4 b = *(const float4*)&Bs[k][tx * 4];
            acc[0][0] += a.x * b.x; acc[0][1] += a.x * b.y; acc[0][2] += a.x * b.z; acc[0][3] += a.x * b.w;
            acc[1][0] += a.y * b.x; acc[1][1] += a.y * b.y; acc[1][2] += a.y * b.z; acc[1][3] += a.y * b.w;
            acc[2][0] += a.z * b.x; acc[2][1] += a.z * b.y; acc[2][2] += a.z * b.z; acc[2][3] += a.z * b.w;
            acc[3][0] += a.w * b.x; acc[3][1] += a.w * b.y; acc[3][2] += a.w * b.z; acc[3][3] += a.w * b.w;
        }
        __syncthreads();
    }
    int n = n0 + tx * 4;
    const float* bi = (n < 1024) ? &bf[n] : &bb[n - 1024];
    float4 bias = *(const float4*)bi;
    #pragma unroll
    for (int i = 0; i < 4; ++i) {
        int v = v0 + ty * 4 + i;
        if (v < VOCAB) {
            float4 o;
            o.x = acc[i][0] + bias.x; o.y = acc[i][1] + bias.y;
            o.z = acc[i][2] + bias.z; o.w = acc[i][3] + bias.w;
            *(float4*)&table[(size_t)v * 2048 + n] = o;
        }
    }
}

// ---------------- K2: clustered LSTM recurrence, W fully LDS-resident ----------
// Grid 256 = 1 block/CU (LDS-forced). Cluster = 8 blocks sharing XCD (bid%8):
//   xcd = bid&7, slot = bid>>3, cluster = xcd*4 + (slot>>3), myb = slot&7.
// Cluster handles 8 batches of one dir; block myb owns h-dims [32*myb,32*myb+32)
// = 128 gate rows, W-slice 128 KB in LDS (loaded ONCE -> no per-step W stream).
// Per step: block computes its 128 rows x 8 batches, updates c,h for its dims,
// publishes h-chunk (1 KB) to L2, polls 7 peer tags, copies full h back to LDS.
// Tag protocol: monotonic step tags + 2-slot ring; stale tags (prev replay)
// never match polled values; data-dependency provides backpressure (max skew 1).
// Thread map (256 thr): t = bh*128 + d*4 + g  (bh=batch-half, d=dim, g=gate).
// Gate exchange i,f,g,o via __shfl_down within 4-lane groups (no LDS bounce).

#define SWZ(lr) ((((lr) & 7) + (((lr) >> 5) << 1)) & 7)

__global__ __launch_bounds__(256) void k_lstm_cl(
    const int* __restrict__ ids, const float* __restrict__ Whhf,
    const float* __restrict__ Whhb, const float* __restrict__ table,
    const float* __restrict__ Wout, float* __restrict__ emp,
    float* hx, int* tagbuf) {
    extern __shared__ float sh_w[];            // [128][256] swizzled = 128 KB
    __shared__ float h_cur[8][256];            // 8 KB
    __shared__ float wout_s[NT][257];          // padded: bank (tag+k)%32
    __shared__ int   sh_id[2][8];

    const int t   = threadIdx.x;
    const int bid = blockIdx.x;
    const int xcd = bid & 7, slot = bid >> 3;
    const int cluster = xcd * 4 + (slot >> 3); // 0..31
    const int myb = slot & 7;                  // 0..7 position in cluster
    const int dir = cluster & 1;
    const int oct = cluster >> 1;              // batch octet 0..15
    const int gbatch = oct * 8 + myb;          // batch this block emits

    const int bh = t >> 7;
    const int d  = (t >> 2) & 31;
    const int g  = t & 3;
    const int lr = g * 32 + d;                 // local row 0..127
    const int gr = g * 256 + myb * 32 + d;     // global gate row 0..1023

    const float* Whh = dir ? Whhb : Whhf;

    // stage wout slice (dir half)
    for (int idx = t; idx < NT * 256; idx += 256)
        wout_s[idx >> 8][idx & 255] = Wout[(idx >> 8) * 512 + dir * 256 + (idx & 255)];
    // stage W-slice into LDS, coalesced global reads, XOR-swizzled store
    for (int i = 0; i < 32; ++i) {
        int idx = i * 256 + t;
        int slr = idx >> 6, k4 = idx & 63;
        int sgr = (slr >> 5) * 256 + myb * 32 + (slr & 31);
        float4 w = *(const float4*)(Whh + (size_t)sgr * 256 + k4 * 4);
        *(float4*)(sh_w + slr * 256 + 4 * (k4 ^ SWZ(slr))) = w;
    }
    for (int idx = t; idx < 2048; idx += 256) ((float*)h_cur)[idx] = 0.f;
    if (t < 8) sh_id[0][t] = ids[(oct * 8 + t) * SEQ + (dir ? SEQ - 1 : 0)];
    float c0 = 0.f, c1 = 0.f, c2 = 0.f, c3 = 0.f;
    __syncthreads();

    // prefetch xg for it=0
    float xn0, xn1, xn2, xn3;
    {
        const float* tb0 = table + (size_t)sh_id[0][4*bh+0] * 2048 + dir * 1024;
        const float* tb1 = table + (size_t)sh_id[0][4*bh+1] * 2048 + dir * 1024;
        const float* tb2 = table + (size_t)sh_id[0][4*bh+2] * 2048 + dir * 1024;
        const float* tb3 = table + (size_t)sh_id[0][4*bh+3] * 2048 + dir * 1024;
        xn0 = tb0[gr]; xn1 = tb1[gr]; xn2 = tb2[gr]; xn3 = tb3[gr];
    }

    const float4* hb0 = (const float4*)h_cur[4*bh+0];
    const float4* hb1 = (const float4*)h_cur[4*bh+1];
    const float4* hb2 = (const float4*)h_cur[4*bh+2];
    const float4* hb3 = (const float4*)h_cur[4*bh+3];
    const float* wrow = sh_w + lr * 256;
    const int swz = SWZ(lr);

    #pragma unroll 1
    for (int it = 0; it < SEQ; ++it) {
        // emission for h_{it-1} (this block's batch only); h_cur == h_{it-1}
        if (it > 0 && t < NT) {
            int sp = dir ? (SEQ - it) : (it - 1);
            float p = 0.f;
            #pragma unroll 4
            for (int k = 0; k < 256; ++k) p += wout_s[t][k] * h_cur[myb][k];
            emp[(((size_t)(dir * BATCH) + gbatch) * SEQ + sp) * NT + t] = p;
        }

        // dots: 4 batches x own row, h from LDS (broadcast), W swizzled
        float a0 = 0.f, a1 = 0.f, a2 = 0.f, a3 = 0.f;
        #pragma unroll 4
        for (int k4 = 0; k4 < 64; ++k4) {
            float4 w  = *(const float4*)(wrow + 4 * (k4 ^ swz));
            float4 h0 = hb0[k4], h1 = hb1[k4], h2 = hb2[k4], h3 = hb3[k4];
            a0 += w.x*h0.x + w.y*h0.y + w.z*h0.z + w.w*h0.w;
            a1 += w.x*h1.x + w.y*h1.y + w.z*h1.z + w.w*h1.w;
            a2 += w.x*h2.x + w.y*h2.y + w.z*h2.z + w.w*h2.w;
            a3 += w.x*h3.x + w.y*h3.y + w.z*h3.z + w.w*h3.w;
        }
        a0 += xn0; a1 += xn1; a2 += xn2; a3 += xn3;

        // gather f,g,o into g==0 lanes (4-lane groups, wave-local)
        float f0 = __shfl_down(a0, 1), q0 = __shfl_down(a0, 2), o0 = __shfl_down(a0, 3);
        float f1 = __shfl_down(a1, 1), q1 = __shfl_down(a1, 2), o1 = __shfl_down(a1, 3);
        float f2 = __shfl_down(a2, 1), q2 = __shfl_down(a2, 2), o2 = __shfl_down(a2, 3);
        float f3 = __shfl_down(a3, 1), q3 = __shfl_down(a3, 2), o3 = __shfl_down(a3, 3);

        __syncthreads();   // all h_cur reads (dots + emission) done

        const int p = it & 1;
        float* hxp = hx + (size_t)p * 65536 + (size_t)cluster * 2048;
        if (g == 0) {
            float hh0, hh1, hh2, hh3;
            {
                float si = 1.f/(1.f+expf(-a0)), sf = 1.f/(1.f+expf(-f0));
                float so = 1.f/(1.f+expf(-o0)); float tg = tanhf(q0);
                c0 = sf * c0 + si * tg; hh0 = so * tanhf(c0);
            }
            {
                float si = 1.f/(1.f+expf(-a1)), sf = 1.f/(1.f+expf(-f1));
                float so = 1.f/(1.f+expf(-o1)); float tg = tanhf(q1);
                c1 = sf * c1 + si * tg; hh1 = so * tanhf(c1);
            }
            {
                float si = 1.f/(1.f+expf(-a2)), sf = 1.f/(1.f+expf(-f2));
                float so = 1.f/(1.f+expf(-o2)); float tg = tanhf(q2);
                c2 = sf * c2 + si * tg; hh2 = so * tanhf(c2);
            }
            {
                float si = 1.f/(1.f+expf(-a3)), sf = 1.f/(1.f+expf(-f3));
                float so = 1.f/(1.f+expf(-o3)); float tg = tanhf(q3);
                c3 = sf * c3 + si * tg; hh3 = so * tanhf(c3);
            }
            int D = myb * 32 + d;
            h_cur[4*bh+0][D] = hh0; h_cur[4*bh+1][D] = hh1;
            h_cur[4*bh+2][D] = hh2; h_cur[4*bh+3][D] = hh3;
            hxp[(myb*8 + 4*bh+0)*32 + d] = hh0;
            hxp[(myb*8 + 4*bh+1)*32 + d] = hh1;
            hxp[(myb*8 + 4*bh+2)*32 + d] = hh2;
            hxp[(myb*8 + 4*bh+3)*32 + d] = hh3;
            __threadfence();   // drain this wave's h stores to device scope
        }
        __syncthreads();       // all blocks' lanes fenced before tag publish

        int* tags = tagbuf + p * 256 + cluster * 8;
        if (t == 0)
            __hip_atomic_store(&tags[myb], it, __ATOMIC_RELEASE, __HIP_MEMORY_SCOPE_AGENT);
        if (t >= 8 && t < 16 && it < SEQ - 1)
            sh_id[(it + 1) & 1][t - 8] = ids[(oct * 8 + (t - 8)) * SEQ + (dir ? SEQ - 2 - it : it + 1)];
        if (t < 8 && t != myb) {
            while (__hip_atomic_load(&tags[t], __ATOMIC_ACQUIRE, __HIP_MEMORY_SCOPE_AGENT) != it)
                __builtin_amdgcn_s_sleep(2);
        }
        __syncthreads();

        // copy full h_it from hx into LDS (agent-scope loads: L1-bypass)
        #pragma unroll
        for (int j = 0; j < 8; ++j) {
            int idx = t + 256 * j;
            float v = __hip_atomic_load(hxp + idx, __ATOMIC_RELAXED, __HIP_MEMORY_SCOPE_AGENT);
            int pm = idx >> 8, bq = (idx >> 5) & 7, dd = idx & 31;
            h_cur[bq][pm * 32 + dd] = v;
        }
        __syncthreads();

        // prefetch xg for it+1
        if (it < SEQ - 1) {
            const int* idp = sh_id[(it + 1) & 1];
            const float* tb0 = table + (size_t)idp[4*bh+0] * 2048 + dir * 1024;
            const float* tb1 = table + (size_t)idp[4*bh+1] * 2048 + dir * 1024;
            const float* tb2 = table + (size_t)idp[4*bh+2] * 2048 + dir * 1024;
            const float* tb3 = table + (size_t)idp[4*bh+3] * 2048 + dir * 1024;
            xn0 = tb0[gr]; xn1 = tb1[gr]; xn2 = tb2[gr]; xn3 = tb3[gr];
        }
    }

    // final emission for h_{511}
    if (t < NT) {
        int sp = dir ? 0 : (SEQ - 1);
        float pe = 0.f;
        #pragma unroll 4
        for (int k = 0; k < 256; ++k) pe += wout_s[t][k] * h_cur[myb][k];
        emp[(((size_t)(dir * BATCH) + gbatch) * SEQ + sp) * NT + t] = pe;
    }
}

// ---------------- K3: Viterbi decode per batch ----------------
__global__ __launch_bounds__(64) void k_viterbi(
    const float* __restrict__ emp, const float* __restrict__ b_out,
    const float* __restrict__ start_t, const float* __restrict__ end_t,
    const float* __restrict__ trans, const void* __restrict__ maskp,
    const int* __restrict__ mask_is_bool, int* __restrict__ out) {
    __shared__ float sh_em[SEQ][NT];
    __shared__ float sh_score[NT];
    __shared__ float sh_trans[NT * NT];
    __shared__ unsigned char sh_mask[SEQ];
    __shared__ unsigned char sh_hist[SEQ - 1][NT];
    __shared__ unsigned char sh_tags[SEQ];
    int b = blockIdx.x;
    int t = threadIdx.x;
    int isb = *mask_is_bool;
    for (int idx = t; idx < SEQ * NT; idx += 64) {
        int s = idx / NT, tg = idx % NT;
        sh_em[s][tg] = emp[((size_t)b * SEQ + s) * NT + tg]
                     + emp[(((size_t)BATCH + b) * SEQ + s) * NT + tg]
                     + b_out[tg];
    }
    if (isb) {
        const unsigned char* m8 = (const unsigned char*)maskp;
        for (int idx = t; idx < SEQ; idx += 64) sh_mask[idx] = m8[b * SEQ + idx];
    } else {
        const int* m32 = (const int*)maskp;
        for (int idx = t; idx < SEQ; idx += 64) sh_mask[idx] = (unsigned char)(m32[b * SEQ + idx] != 0);
    }
    for (int idx = t; idx < NT * NT; idx += 64) sh_trans[idx] = trans[idx];
    __syncthreads();
    float sc = 0.f;
    if (t < NT) { sc = start_t[t] + sh_em[0][t]; sh_score[t] = sc; }
    __syncthreads();
    for (int s = 1; s < SEQ; ++s) {
        if (t < NT) {
            float m = -3.4e38f; int bp = 0;
            #pragma unroll
            for (int i = 0; i < NT; ++i) {
                float v = sh_score[i] + sh_trans[i * NT + t];
                if (v > m) { m = v; bp = i; }
            }
            sh_hist[s - 1][t] = (unsigned char)bp;
            float best = m + sh_em[s][t];
            if (sh_mask[s]) sc = best;
        }
        __syncthreads();
        if (t < NT) sh_score[t] = sc;
        __syncthreads();
    }
    if (t == 0) {
        float bb = -3.4e38f; int tag = 0;
        for (int j = 0; j < NT; ++j) {
            float v = sh_score[j] + end_t[j];
            if (v > bb) { bb = v; tag = j; }
        }
        for (int pos = SEQ - 1; pos >= 1; --pos) {
            sh_tags[pos] = (unsigned char)tag;
            if (sh_mask[pos]) tag = sh_hist[pos - 1][tag];
        }
        sh_tags[0] = (unsigned char)tag;
    }
    __syncthreads();
    for (int idx = t; idx < SEQ; idx += 64) {
        out[b * SEQ + idx] = sh_mask[idx] ? (int)sh_tags[idx] : 0;
    }
}

extern "C" void kernel_launch(void* const* d_in, const int* in_sizes, int n_in,
                              void* d_out, int out_size, void* d_ws, size_t ws_size,
                              hipStream_t stream) {
    const int*   ids  = (const int*)d_in[0];
    const void*  mask = d_in[1];
    const float* emb  = (const float*)d_in[2];
    const float* Wihf = (const float*)d_in[3];
    const float* Whhf = (const float*)d_in[4];
    const float* bfv  = (const float*)d_in[5];
    const float* Wihb = (const float*)d_in[6];
    const float* Whhb = (const float*)d_in[7];
    const float* bbv  = (const float*)d_in[8];
    const float* Wout = (const float*)d_in[9];
    const float* bout = (const float*)d_in[10];
    const float* st   = (const float*)d_in[11];
    const float* en   = (const float*)d_in[12];
    const float* tr   = (const float*)d_in[13];
    int* out = (int*)d_out;

    char* ws = (char*)d_ws;
    float* table = (float*)ws;                                       // 245,760,000 B
    float* emp   = (float*)(ws + 245760000);                         //   4,718,592 B
    float* hx    = (float*)(ws + 245760000 + 4718592);               //     524,288 B
    int*   tags  = (int*)(ws + 245760000 + 4718592 + 524288);        //       2,048 B
    int*   flag  = (int*)(ws + 245760000 + 4718592 + 524288 + 2048); //           4 B

    k_detect<<<1, 128, 0, stream>>>((const unsigned char*)mask, flag);
    dim3 g1(32, 469);
    k_table_gemm<<<g1, 256, 0, stream>>>(emb, Wihf, Wihb, bfv, bbv, table);
    k_lstm_cl<<<256, 256, 128 * 1024, stream>>>(ids, Whhf, Whhb, table, Wout, emp, hx, tags);
    k_viterbi<<<128, 64, 0, stream>>>(emp, bout, st, en, tr, mask, flag, out);
}

// Round 9
// 6839.606 us; speedup vs baseline: 2.7284x; 2.7284x over previous
//
#include <hip/hip_runtime.h>
#include <hip/hip_bf16.h>

#define SEQ   512
#define BATCH 128
#define VOCAB 30000
#define EDIM  256
#define HDIM  256
#define NT    9

// ---------------- K0b: detect mask storage dtype ----------------
__global__ void k_detect(const unsigned char* __restrict__ m, int* __restrict__ flag) {
    __shared__ int ok_sh;
    if (threadIdx.x == 0) ok_sh = 1;
    __syncthreads();
    int b = threadIdx.x;  // 128 threads, one row each
    const uint4* row = (const uint4*)(m + b * SEQ);
    int ok = 1, prev = 1;
    for (int i = 0; i < SEQ / 16; ++i) {
        uint4 v = row[i];
        unsigned w[4] = {v.x, v.y, v.z, v.w};
        #pragma unroll
        for (int wi = 0; wi < 4; ++wi) {
            #pragma unroll
            for (int j = 0; j < 4; ++j) {
                int byte = (w[wi] >> (8 * j)) & 255;
                if (byte > 1 || byte > prev) ok = 0;
                prev = byte;
            }
        }
    }
    if (!ok) atomicAnd(&ok_sh, 0);
    __syncthreads();
    if (threadIdx.x == 0) *flag = ok_sh;
}

// ---------------- K1: table[v][n] = embed[v] . Wcat[n] + bias[n] ----------------
__global__ __launch_bounds__(256) void k_table_gemm(
    const float* __restrict__ emb, const float* __restrict__ Wf,
    const float* __restrict__ Wb, const float* __restrict__ bf,
    const float* __restrict__ bb, float* __restrict__ table) {
    __shared__ __align__(16) float As[64][68];  // [k][m]
    __shared__ __align__(16) float Bs[64][68];  // [k][n]
    int t  = threadIdx.x;
    int tx = t & 15, ty = t >> 4;
    int n0 = blockIdx.x * 64;
    int v0 = blockIdx.y * 64;
    float acc[4][4] = {};
    for (int kc = 0; kc < 4; ++kc) {
        #pragma unroll
        for (int rr = 0; rr < 4; ++rr) {
            int slot = t + rr * 256;
            int m = slot >> 4, kq = slot & 15;
            int v = v0 + m;
            float4 a = (v < VOCAB)
                ? *(const float4*)&emb[v * EDIM + kc * 64 + kq * 4]
                : make_float4(0.f, 0.f, 0.f, 0.f);
            As[kq * 4 + 0][m] = a.x; As[kq * 4 + 1][m] = a.y;
            As[kq * 4 + 2][m] = a.z; As[kq * 4 + 3][m] = a.w;
            int n = n0 + m;
            const float* Wrow = (n < 1024) ? &Wf[n * 256] : &Wb[(n - 1024) * 256];
            float4 bvec = *(const float4*)&Wrow[kc * 64 + kq * 4];
            Bs[kq * 4 + 0][m] = bvec.x; Bs[kq * 4 + 1][m] = bvec.y;
            Bs[kq * 4 + 2][m] = bvec.z; Bs[kq * 4 + 3][m] = bvec.w;
        }
        __syncthreads();
        #pragma unroll
        for (int k = 0; k < 64; ++k) {
            float4 a = *(const float4*)&As[k][ty * 4];
            float4 b = *(const float4*)&Bs[k][tx * 4];
            acc[0][0] += a.x * b.x; acc[0][1] += a.x * b.y; acc[0][2] += a.x * b.z; acc[0][3] += a.x * b.w;
            acc[1][0] += a.y * b.x; acc[1][1] += a.y * b.y; acc[1][2] += a.y * b.z; acc[1][3] += a.y * b.w;
            acc[2][0] += a.z * b.x; acc[2][1] += a.z * b.y; acc[2][2] += a.z * b.z; acc[2][3] += a.z * b.w;
            acc[3][0] += a.w * b.x; acc[3][1] += a.w * b.y; acc[3][2] += a.w * b.z; acc[3][3] += a.w * b.w;
        }
        __syncthreads();
    }
    int n = n0 + tx * 4;
    const float* bi = (n < 1024) ? &bf[n] : &bb[n - 1024];
    float4 bias = *(const float4*)bi;
    #pragma unroll
    for (int i = 0; i < 4; ++i) {
        int v = v0 + ty * 4 + i;
        if (v < VOCAB) {
            float4 o;
            o.x = acc[i][0] + bias.x; o.y = acc[i][1] + bias.y;
            o.z = acc[i][2] + bias.z; o.w = acc[i][3] + bias.w;
            *(float4*)&table[(size_t)v * 2048 + n] = o;
        }
    }
}

// ---------------- K2: clustered LSTM, W LDS-resident, L3 h-exchange ----------
// See theory: no per-step __threadfence (r8's buffer_wbl2 bomb); relaxed-atomic
// agent stores/loads (sc0sc1 -> L3 coherent point, XCD-placement-independent);
// conflict-free sh_w[k][128] layout; parallel emission.
__global__ __launch_bounds__(256) void k_lstm_cl(
    const int* __restrict__ ids, const float* __restrict__ Whhf,
    const float* __restrict__ Whhb, const float* __restrict__ table,
    const float* __restrict__ Wout, float* __restrict__ emp,
    float* hx, int* tagbuf) {
    extern __shared__ float sh_w[];            // [256][128] = 128 KB
    __shared__ float h_cur[8][256];            // 8 KB
    __shared__ float sh_g[8][128];             // 4 KB  [batch][g*32+dd]
    __shared__ float wout_s[NT][257];
    __shared__ int   sh_id[2][8];

    const int t   = threadIdx.x;
    const int bid = blockIdx.x;
    const int cluster = bid >> 3;              // 0..31
    const int myb = bid & 7;
    const int dir = cluster & 1;
    const int oct = cluster >> 1;
    const int gbatch = oct * 8 + myb;

    const int bh = t >> 7;                     // batch-half for dot
    const int rr = t & 127;                    // local gate row
    const int gr = (rr >> 5) * 256 + myb * 32 + (rr & 31);

    const int nb = t >> 5;                     // nonlin batch 0..7
    const int nd = t & 31;                     // nonlin dim-in-slice

    const int etg = t >> 4;                    // emission tag (t<144)
    const int el  = t & 15;

    const float* Whh = dir ? Whhb : Whhf;

    for (int idx = t; idx < NT * 256; idx += 256)
        wout_s[idx >> 8][idx & 255] = Wout[(idx >> 8) * 512 + dir * 256 + (idx & 255)];
    {
        int row2 = t >> 1, half = t & 1;
        int g2 = (row2 >> 5) * 256 + myb * 32 + (row2 & 31);
        const float4* src = (const float4*)(Whh + (size_t)g2 * 256 + half * 128);
        #pragma unroll 4
        for (int i = 0; i < 32; ++i) {
            float4 w = src[i];
            int k = half * 128 + i * 4;
            sh_w[(k + 0) * 128 + row2] = w.x;
            sh_w[(k + 1) * 128 + row2] = w.y;
            sh_w[(k + 2) * 128 + row2] = w.z;
            sh_w[(k + 3) * 128 + row2] = w.w;
        }
    }
    for (int idx = t; idx < 2048; idx += 256) ((float*)h_cur)[idx] = 0.f;
    if (t < 8) sh_id[0][t] = ids[(oct * 8 + t) * SEQ + (dir ? SEQ - 1 : 0)];
    float c_state = 0.f;
    __syncthreads();

    float xn0, xn1, xn2, xn3;
    {
        const float* tb0 = table + (size_t)sh_id[0][4*bh+0] * 2048 + dir * 1024;
        const float* tb1 = table + (size_t)sh_id[0][4*bh+1] * 2048 + dir * 1024;
        const float* tb2 = table + (size_t)sh_id[0][4*bh+2] * 2048 + dir * 1024;
        const float* tb3 = table + (size_t)sh_id[0][4*bh+3] * 2048 + dir * 1024;
        xn0 = tb0[gr]; xn1 = tb1[gr]; xn2 = tb2[gr]; xn3 = tb3[gr];
    }

    #pragma unroll 1
    for (int it = 0; it < SEQ; ++it) {
        if (it > 0 && t < 144) {
            int sp = dir ? (SEQ - it) : (it - 1);
            float p = 0.f;
            #pragma unroll
            for (int j = 0; j < 16; ++j)
                p += wout_s[etg][el + 16 * j] * h_cur[myb][el + 16 * j];
            p += __shfl_xor(p, 1); p += __shfl_xor(p, 2);
            p += __shfl_xor(p, 4); p += __shfl_xor(p, 8);
            if (el == 0)
                emp[(((size_t)(dir * BATCH) + gbatch) * SEQ + sp) * NT + etg] = p;
        }

        float a0 = xn0, a1 = xn1, a2 = xn2, a3 = xn3;
        const float* h0p = h_cur[4*bh+0];
        const float* h1p = h_cur[4*bh+1];
        const float* h2p = h_cur[4*bh+2];
        const float* h3p = h_cur[4*bh+3];
        #pragma unroll 8
        for (int k4 = 0; k4 < 64; ++k4) {
            float4 h0 = *(const float4*)&h0p[k4*4];
            float4 h1 = *(const float4*)&h1p[k4*4];
            float4 h2 = *(const float4*)&h2p[k4*4];
            float4 h3 = *(const float4*)&h3p[k4*4];
            float w0 = sh_w[(k4*4+0)*128 + rr];
            float w1 = sh_w[(k4*4+1)*128 + rr];
            float w2 = sh_w[(k4*4+2)*128 + rr];
            float w3 = sh_w[(k4*4+3)*128 + rr];
            a0 += w0*h0.x + w1*h0.y + w2*h0.z + w3*h0.w;
            a1 += w0*h1.x + w1*h1.y + w2*h1.z + w3*h1.w;
            a2 += w0*h2.x + w1*h2.y + w2*h2.z + w3*h2.w;
            a3 += w0*h3.x + w1*h3.y + w2*h3.z + w3*h3.w;
        }
        sh_g[4*bh+0][rr] = a0;
        sh_g[4*bh+1][rr] = a1;
        sh_g[4*bh+2][rr] = a2;
        sh_g[4*bh+3][rr] = a3;
        __syncthreads();   // gates ready; h_cur reads done

        const int p = it & 1;
        float* hxp = hx + (size_t)p * 65536 + (size_t)cluster * 2048;
        {
            float iv = sh_g[nb][0*32 + nd];
            float fv = sh_g[nb][1*32 + nd];
            float gv = sh_g[nb][2*32 + nd];
            float ov = sh_g[nb][3*32 + nd];
            float si = 1.f / (1.f + expf(-iv));
            float sf = 1.f / (1.f + expf(-fv));
            float so = 1.f / (1.f + expf(-ov));
            float tg = tanhf(gv);
            c_state = sf * c_state + si * tg;
            float hh = so * tanhf(c_state);
            h_cur[nb][myb * 32 + nd] = hh;
            __hip_atomic_store(&hxp[nb * 256 + myb * 32 + nd], hh,
                               __ATOMIC_RELAXED, __HIP_MEMORY_SCOPE_AGENT);
        }
        asm volatile("s_waitcnt vmcnt(0)" ::: "memory");
        __syncthreads();   // all waves' h stores globally complete

        int* tags = tagbuf + p * 256 + cluster * 8;
        if (t == 0)
            __hip_atomic_store(&tags[myb], it, __ATOMIC_RELAXED, __HIP_MEMORY_SCOPE_AGENT);
        if (t >= 8 && t < 16 && it < SEQ - 1)
            sh_id[(it + 1) & 1][t - 8] = ids[(oct * 8 + (t - 8)) * SEQ + (dir ? SEQ - 2 - it : it + 1)];
        if (t < 8 && t != myb) {
            while (__hip_atomic_load(&tags[t], __ATOMIC_RELAXED, __HIP_MEMORY_SCOPE_AGENT) != it)
                __builtin_amdgcn_s_sleep(1);
        }
        __syncthreads();

        #pragma unroll
        for (int j = 0; j < 8; ++j) {
            int idx = t + 256 * j;
            float v = __hip_atomic_load(&hxp[idx], __ATOMIC_RELAXED, __HIP_MEMORY_SCOPE_AGENT);
            h_cur[idx >> 8][idx & 255] = v;
        }
        __syncthreads();

        if (it < SEQ - 1) {
            const int* idp = sh_id[(it + 1) & 1];
            const float* tb0 = table + (size_t)idp[4*bh+0] * 2048 + dir * 1024;
            const float* tb1 = table + (size_t)idp[4*bh+1] * 2048 + dir * 1024;
            const float* tb2 = table + (size_t)idp[4*bh+2] * 2048 + dir * 1024;
            const float* tb3 = table + (size_t)idp[4*bh+3] * 2048 + dir * 1024;
            xn0 = tb0[gr]; xn1 = tb1[gr]; xn2 = tb2[gr]; xn3 = tb3[gr];
        }
    }

    if (t < 144) {
        int sp = dir ? 0 : (SEQ - 1);
        float p = 0.f;
        #pragma unroll
        for (int j = 0; j < 16; ++j)
            p += wout_s[etg][el + 16 * j] * h_cur[myb][el + 16 * j];
        p += __shfl_xor(p, 1); p += __shfl_xor(p, 2);
        p += __shfl_xor(p, 4); p += __shfl_xor(p, 8);
        if (el == 0)
            emp[(((size_t)(dir * BATCH) + gbatch) * SEQ + sp) * NT + etg] = p;
    }
}

// ---------------- K3: Viterbi decode per batch ----------------
__global__ __launch_bounds__(64) void k_viterbi(
    const float* __restrict__ emp, const float* __restrict__ b_out,
    const float* __restrict__ start_t, const float* __restrict__ end_t,
    const float* __restrict__ trans, const void* __restrict__ maskp,
    const int* __restrict__ mask_is_bool, int* __restrict__ out) {
    __shared__ float sh_em[SEQ][NT];
    __shared__ float sh_score[NT];
    __shared__ float sh_trans[NT * NT];
    __shared__ unsigned char sh_mask[SEQ];
    __shared__ unsigned char sh_hist[SEQ - 1][NT];
    __shared__ unsigned char sh_tags[SEQ];
    int b = blockIdx.x;
    int t = threadIdx.x;
    int isb = *mask_is_bool;
    for (int idx = t; idx < SEQ * NT; idx += 64) {
        int s = idx / NT, tg = idx % NT;
        sh_em[s][tg] = emp[((size_t)b * SEQ + s) * NT + tg]
                     + emp[(((size_t)BATCH + b) * SEQ + s) * NT + tg]
                     + b_out[tg];
    }
    if (isb) {
        const unsigned char* m8 = (const unsigned char*)maskp;
        for (int idx = t; idx < SEQ; idx += 64) sh_mask[idx] = m8[b * SEQ + idx];
    } else {
        const int* m32 = (const int*)maskp;
        for (int idx = t; idx < SEQ; idx += 64) sh_mask[idx] = (unsigned char)(m32[b * SEQ + idx] != 0);
    }
    for (int idx = t; idx < NT * NT; idx += 64) sh_trans[idx] = trans[idx];
    __syncthreads();
    float sc = 0.f;
    if (t < NT) { sc = start_t[t] + sh_em[0][t]; sh_score[t] = sc; }
    __syncthreads();
    for (int s = 1; s < SEQ; ++s) {
        if (t < NT) {
            float m = -3.4e38f; int bp = 0;
            #pragma unroll
            for (int i = 0; i < NT; ++i) {
                float v = sh_score[i] + sh_trans[i * NT + t];
                if (v > m) { m = v; bp = i; }
            }
            sh_hist[s - 1][t] = (unsigned char)bp;
            float best = m + sh_em[s][t];
            if (sh_mask[s]) sc = best;
        }
        __syncthreads();
        if (t < NT) sh_score[t] = sc;
        __syncthreads();
    }
    if (t == 0) {
        float bb = -3.4e38f; int tag = 0;
        for (int j = 0; j < NT; ++j) {
            float v = sh_score[j] + end_t[j];
            if (v > bb) { bb = v; tag = j; }
        }
        for (int pos = SEQ - 1; pos >= 1; --pos) {
            sh_tags[pos] = (unsigned char)tag;
            if (sh_mask[pos]) tag = sh_hist[pos - 1][tag];
        }
        sh_tags[0] = (unsigned char)tag;
    }
    __syncthreads();
    for (int idx = t; idx < SEQ; idx += 64) {
        out[b * SEQ + idx] = sh_mask[idx] ? (int)sh_tags[idx] : 0;
    }
}

extern "C" void kernel_launch(void* const* d_in, const int* in_sizes, int n_in,
                              void* d_out, int out_size, void* d_ws, size_t ws_size,
                              hipStream_t stream) {
    const int*   ids  = (const int*)d_in[0];
    const void*  mask = d_in[1];
    const float* emb  = (const float*)d_in[2];
    const float* Wihf = (const float*)d_in[3];
    const float* Whhf = (const float*)d_in[4];
    const float* bfv  = (const float*)d_in[5];
    const float* Wihb = (const float*)d_in[6];
    const float* Whhb = (const float*)d_in[7];
    const float* bbv  = (const float*)d_in[8];
    const float* Wout = (const float*)d_in[9];
    const float* bout = (const float*)d_in[10];
    const float* st   = (const float*)d_in[11];
    const float* en   = (const float*)d_in[12];
    const float* tr   = (const float*)d_in[13];
    int* out = (int*)d_out;

    char* ws = (char*)d_ws;
    float* table = (float*)ws;                                       // 245,760,000 B
    float* emp   = (float*)(ws + 245760000);                         //   4,718,592 B
    float* hx    = (float*)(ws + 245760000 + 4718592);               //     524,288 B
    int*   tags  = (int*)(ws + 245760000 + 4718592 + 524288);        //       2,048 B
    int*   flag  = (int*)(ws + 245760000 + 4718592 + 524288 + 2048); //           4 B

    k_detect<<<1, 128, 0, stream>>>((const unsigned char*)mask, flag);
    dim3 g1(32, 469);
    k_table_gemm<<<g1, 256, 0, stream>>>(emb, Wihf, Wihb, bfv, bbv, table);
    k_lstm_cl<<<256, 256, 131072, stream>>>(ids, Whhf, Whhb, table, Wout, emp, hx, tags);
    k_viterbi<<<128, 64, 0, stream>>>(emp, bout, st, en, tr, mask, flag, out);
}

// Round 10
// 4469.749 us; speedup vs baseline: 4.1751x; 1.5302x over previous
//
#include <hip/hip_runtime.h>
#include <hip/hip_bf16.h>

#define SEQ   512
#define BATCH 128
#define VOCAB 30000
#define EDIM  256
#define HDIM  256
#define NT    9

// ---------------- K0b: detect mask storage dtype ----------------
__global__ void k_detect(const unsigned char* __restrict__ m, int* __restrict__ flag) {
    __shared__ int ok_sh;
    if (threadIdx.x == 0) ok_sh = 1;
    __syncthreads();
    int b = threadIdx.x;  // 128 threads, one row each
    const uint4* row = (const uint4*)(m + b * SEQ);
    int ok = 1, prev = 1;
    for (int i = 0; i < SEQ / 16; ++i) {
        uint4 v = row[i];
        unsigned w[4] = {v.x, v.y, v.z, v.w};
        #pragma unroll
        for (int wi = 0; wi < 4; ++wi) {
            #pragma unroll
            for (int j = 0; j < 4; ++j) {
                int byte = (w[wi] >> (8 * j)) & 255;
                if (byte > 1 || byte > prev) ok = 0;
                prev = byte;
            }
        }
    }
    if (!ok) atomicAnd(&ok_sh, 0);
    __syncthreads();
    if (threadIdx.x == 0) *flag = ok_sh;
}

// ---------------- K1: table[v][n] = embed[v] . Wcat[n] + bias[n] ----------------
__global__ __launch_bounds__(256) void k_table_gemm(
    const float* __restrict__ emb, const float* __restrict__ Wf,
    const float* __restrict__ Wb, const float* __restrict__ bf,
    const float* __restrict__ bb, float* __restrict__ table) {
    __shared__ __align__(16) float As[64][68];  // [k][m]
    __shared__ __align__(16) float Bs[64][68];  // [k][n]
    int t  = threadIdx.x;
    int tx = t & 15, ty = t >> 4;
    int n0 = blockIdx.x * 64;
    int v0 = blockIdx.y * 64;
    float acc[4][4] = {};
    for (int kc = 0; kc < 4; ++kc) {
        #pragma unroll
        for (int rr = 0; rr < 4; ++rr) {
            int slot = t + rr * 256;
            int m = slot >> 4, kq = slot & 15;
            int v = v0 + m;
            float4 a = (v < VOCAB)
                ? *(const float4*)&emb[v * EDIM + kc * 64 + kq * 4]
                : make_float4(0.f, 0.f, 0.f, 0.f);
            As[kq * 4 + 0][m] = a.x; As[kq * 4 + 1][m] = a.y;
            As[kq * 4 + 2][m] = a.z; As[kq * 4 + 3][m] = a.w;
            int n = n0 + m;
            const float* Wrow = (n < 1024) ? &Wf[n * 256] : &Wb[(n - 1024) * 256];
            float4 bvec = *(const float4*)&Wrow[kc * 64 + kq * 4];
            Bs[kq * 4 + 0][m] = bvec.x; Bs[kq * 4 + 1][m] = bvec.y;
            Bs[kq * 4 + 2][m] = bvec.z; Bs[kq * 4 + 3][m] = bvec.w;
        }
        __syncthreads();
        #pragma unroll
        for (int k = 0; k < 64; ++k) {
            float4 a = *(const float4*)&As[k][ty * 4];
            float4 b = *(const float4*)&Bs[k][tx * 4];
            acc[0][0] += a.x * b.x; acc[0][1] += a.x * b.y; acc[0][2] += a.x * b.z; acc[0][3] += a.x * b.w;
            acc[1][0] += a.y * b.x; acc[1][1] += a.y * b.y; acc[1][2] += a.y * b.z; acc[1][3] += a.y * b.w;
            acc[2][0] += a.z * b.x; acc[2][1] += a.z * b.y; acc[2][2] += a.z * b.z; acc[2][3] += a.z * b.w;
            acc[3][0] += a.w * b.x; acc[3][1] += a.w * b.y; acc[3][2] += a.w * b.z; acc[3][3] += a.w * b.w;
        }
        __syncthreads();
    }
    int n = n0 + tx * 4;
    const float* bi = (n < 1024) ? &bf[n] : &bb[n - 1024];
    float4 bias = *(const float4*)bi;
    #pragma unroll
    for (int i = 0; i < 4; ++i) {
        int v = v0 + ty * 4 + i;
        if (v < VOCAB) {
            float4 o;
            o.x = acc[i][0] + bias.x; o.y = acc[i][1] + bias.y;
            o.z = acc[i][2] + bias.z; o.w = acc[i][3] + bias.w;
            *(float4*)&table[(size_t)v * 2048 + n] = o;
        }
    }
}

// ---------------- K2: clustered LSTM, W LDS-resident, L3 h-exchange ----------
// 256 blocks x 512 threads (8 waves/CU -> 2/SIMD for latency hiding).
// cluster = bid>>3 (32), myb = bid&7; dir = cluster&1; oct = cluster>>1.
// Block owns dims [myb*32,myb*32+32) = 128 gate rows; W-slice 128 KB LDS,
// swizzled rows for b128 conflict-spread reads.
// Dot thread map: kh = t>>8 (k half), bh = (t>>7)&1 (batch quad), rr = t&127
// (gate row). Partial gates -> sh_gp[batch][row][kh], combined in nonlin.
// Exchange (proven in r9): relaxed agent atomics to L3, vmcnt(0), monotonic
// tags + 2-slot ring, no threadfence.
__global__ __launch_bounds__(512) void k_lstm_cl(
    const int* __restrict__ ids, const float* __restrict__ Whhf,
    const float* __restrict__ Whhb, const float* __restrict__ table,
    const float* __restrict__ Wout, float* __restrict__ emp,
    float* hx, int* tagbuf) {
    extern __shared__ float sh_w[];            // [128 rows][256 k] swz = 128 KB
    __shared__ float h_cur[8][256];            // 8 KB
    __shared__ float sh_gp[8][128][2];         // 8 KB partial gates
    __shared__ float wout_s[NT][257];
    __shared__ int   sh_id[2][8];

    const int t   = threadIdx.x;
    const int bid = blockIdx.x;
    const int cluster = bid >> 3;              // 0..31
    const int myb = bid & 7;
    const int dir = cluster & 1;
    const int oct = cluster >> 1;
    const int gbatch = oct * 8 + myb;

    const int kh = t >> 8;                     // k half 0/1
    const int bh = (t >> 7) & 1;               // batch quad 0/1
    const int rr = t & 127;                    // local gate row
    const int gr = (rr >> 5) * 256 + myb * 32 + (rr & 31);

    const int nb = t >> 5;                     // nonlin batch (t<256)
    const int nd = t & 31;                     // nonlin dim-in-slice

    const int etg = t >> 4;                    // emission tag (t<144)
    const int el  = t & 15;

    const float* Whh = dir ? Whhb : Whhf;

    for (int idx = t; idx < NT * 256; idx += 512)
        wout_s[idx >> 8][idx & 255] = Wout[(idx >> 8) * 512 + dir * 256 + (idx & 255)];
    // stage W-slice: 4 threads/row, 64 k each; swizzled b128 store
    {
        int row = t >> 2, q = t & 3;
        int g2 = (row >> 5) * 256 + myb * 32 + (row & 31);
        const float4* src = (const float4*)(Whh + (size_t)g2 * 256 + q * 64);
        #pragma unroll 4
        for (int i = 0; i < 16; ++i) {
            int k4 = q * 16 + i;
            float4 w = src[i];
            *(float4*)(sh_w + row * 256 + 4 * (k4 ^ (row & 63))) = w;
        }
    }
    for (int idx = t; idx < 2048; idx += 512) ((float*)h_cur)[idx] = 0.f;
    if (t < 8) sh_id[0][t] = ids[(oct * 8 + t) * SEQ + (dir ? SEQ - 1 : 0)];
    float c_state = 0.f;
    __syncthreads();

    // xg prefetch for it=0 (kh==0 threads only: t<256)
    float xn0 = 0.f, xn1 = 0.f, xn2 = 0.f, xn3 = 0.f;
    if (t < 256) {
        const float* tb0 = table + (size_t)sh_id[0][4*bh+0] * 2048 + dir * 1024;
        const float* tb1 = table + (size_t)sh_id[0][4*bh+1] * 2048 + dir * 1024;
        const float* tb2 = table + (size_t)sh_id[0][4*bh+2] * 2048 + dir * 1024;
        const float* tb3 = table + (size_t)sh_id[0][4*bh+3] * 2048 + dir * 1024;
        xn0 = tb0[gr]; xn1 = tb1[gr]; xn2 = tb2[gr]; xn3 = tb3[gr];
    }

    #pragma unroll 1
    for (int it = 0; it < SEQ; ++it) {
        // emission for h_{it-1} (h_cur holds h_{it-1})
        if (it > 0 && t < 144) {
            int sp = dir ? (SEQ - it) : (it - 1);
            float p = 0.f;
            #pragma unroll
            for (int j = 0; j < 16; ++j)
                p += wout_s[etg][el + 16 * j] * h_cur[myb][el + 16 * j];
            p += __shfl_xor(p, 1); p += __shfl_xor(p, 2);
            p += __shfl_xor(p, 4); p += __shfl_xor(p, 8);
            if (el == 0)
                emp[(((size_t)(dir * BATCH) + gbatch) * SEQ + sp) * NT + etg] = p;
        }

        // dot: own gate row x 4 batches x half the k range
        float a0 = xn0, a1 = xn1, a2 = xn2, a3 = xn3;   // xn==0 for kh==1
        const float* h0p = h_cur[4*bh+0];
        const float* h1p = h_cur[4*bh+1];
        const float* h2p = h_cur[4*bh+2];
        const float* h3p = h_cur[4*bh+3];
        const float* wr = sh_w + rr * 256;
        const int rs = rr & 63;
        #pragma unroll 8
        for (int j = 0; j < 32; ++j) {
            int k4 = kh * 32 + j;
            float4 w  = *(const float4*)(wr + 4 * (k4 ^ rs));
            float4 h0 = *(const float4*)&h0p[k4 * 4];
            float4 h1 = *(const float4*)&h1p[k4 * 4];
            float4 h2 = *(const float4*)&h2p[k4 * 4];
            float4 h3 = *(const float4*)&h3p[k4 * 4];
            a0 += w.x*h0.x + w.y*h0.y + w.z*h0.z + w.w*h0.w;
            a1 += w.x*h1.x + w.y*h1.y + w.z*h1.z + w.w*h1.w;
            a2 += w.x*h2.x + w.y*h2.y + w.z*h2.z + w.w*h2.w;
            a3 += w.x*h3.x + w.y*h3.y + w.z*h3.z + w.w*h3.w;
        }
        sh_gp[4*bh+0][rr][kh] = a0;
        sh_gp[4*bh+1][rr][kh] = a1;
        sh_gp[4*bh+2][rr][kh] = a2;
        sh_gp[4*bh+3][rr][kh] = a3;
        __syncthreads();   // partials ready; h_cur reads done

        const int p = it & 1;
        float* hxp = hx + (size_t)p * 65536 + (size_t)cluster * 2048;
        if (t < 256) {
            float iv = sh_gp[nb][nd][0]      + sh_gp[nb][nd][1];
            float fv = sh_gp[nb][32 + nd][0] + sh_gp[nb][32 + nd][1];
            float gv = sh_gp[nb][64 + nd][0] + sh_gp[nb][64 + nd][1];
            float ov = sh_gp[nb][96 + nd][0] + sh_gp[nb][96 + nd][1];
            float si = 1.f / (1.f + expf(-iv));
            float sf = 1.f / (1.f + expf(-fv));
            float so = 1.f / (1.f + expf(-ov));
            float tg = tanhf(gv);
            c_state = sf * c_state + si * tg;
            float hh = so * tanhf(c_state);
            h_cur[nb][myb * 32 + nd] = hh;
            __hip_atomic_store(&hxp[nb * 256 + myb * 32 + nd], hh,
                               __ATOMIC_RELAXED, __HIP_MEMORY_SCOPE_AGENT);
        }
        asm volatile("s_waitcnt vmcnt(0)" ::: "memory");
        __syncthreads();   // all h stores globally complete

        int* tags = tagbuf + p * 256 + cluster * 8;
        if (t == 0)
            __hip_atomic_store(&tags[myb], it, __ATOMIC_RELAXED, __HIP_MEMORY_SCOPE_AGENT);
        if (t >= 8 && t < 16 && it < SEQ - 1)
            sh_id[(it + 1) & 1][t - 8] = ids[(oct * 8 + (t - 8)) * SEQ + (dir ? SEQ - 2 - it : it + 1)];
        if (t < 8 && t != myb) {
            while (__hip_atomic_load(&tags[t], __ATOMIC_RELAXED, __HIP_MEMORY_SCOPE_AGENT) != it)
                __builtin_amdgcn_s_sleep(1);
        }
        __syncthreads();

        // copy full h_it from L3 into LDS
        #pragma unroll
        for (int j = 0; j < 4; ++j) {
            int idx = t + 512 * j;
            float v = __hip_atomic_load(&hxp[idx], __ATOMIC_RELAXED, __HIP_MEMORY_SCOPE_AGENT);
            h_cur[idx >> 8][idx & 255] = v;
        }
        __syncthreads();

        if (t < 256 && it < SEQ - 1) {
            const int* idp = sh_id[(it + 1) & 1];
            const float* tb0 = table + (size_t)idp[4*bh+0] * 2048 + dir * 1024;
            const float* tb1 = table + (size_t)idp[4*bh+1] * 2048 + dir * 1024;
            const float* tb2 = table + (size_t)idp[4*bh+2] * 2048 + dir * 1024;
            const float* tb3 = table + (size_t)idp[4*bh+3] * 2048 + dir * 1024;
            xn0 = tb0[gr]; xn1 = tb1[gr]; xn2 = tb2[gr]; xn3 = tb3[gr];
        }
    }

    // final emission for h_{511}
    if (t < 144) {
        int sp = dir ? 0 : (SEQ - 1);
        float p = 0.f;
        #pragma unroll
        for (int j = 0; j < 16; ++j)
            p += wout_s[etg][el + 16 * j] * h_cur[myb][el + 16 * j];
        p += __shfl_xor(p, 1); p += __shfl_xor(p, 2);
        p += __shfl_xor(p, 4); p += __shfl_xor(p, 8);
        if (el == 0)
            emp[(((size_t)(dir * BATCH) + gbatch) * SEQ + sp) * NT + etg] = p;
    }
}

// ---------------- K3: Viterbi decode per batch ----------------
__global__ __launch_bounds__(64) void k_viterbi(
    const float* __restrict__ emp, const float* __restrict__ b_out,
    const float* __restrict__ start_t, const float* __restrict__ end_t,
    const float* __restrict__ trans, const void* __restrict__ maskp,
    const int* __restrict__ mask_is_bool, int* __restrict__ out) {
    __shared__ float sh_em[SEQ][NT];
    __shared__ float sh_score[NT];
    __shared__ float sh_trans[NT * NT];
    __shared__ unsigned char sh_mask[SEQ];
    __shared__ unsigned char sh_hist[SEQ - 1][NT];
    __shared__ unsigned char sh_tags[SEQ];
    int b = blockIdx.x;
    int t = threadIdx.x;
    int isb = *mask_is_bool;
    for (int idx = t; idx < SEQ * NT; idx += 64) {
        int s = idx / NT, tg = idx % NT;
        sh_em[s][tg] = emp[((size_t)b * SEQ + s) * NT + tg]
                     + emp[(((size_t)BATCH + b) * SEQ + s) * NT + tg]
                     + b_out[tg];
    }
    if (isb) {
        const unsigned char* m8 = (const unsigned char*)maskp;
        for (int idx = t; idx < SEQ; idx += 64) sh_mask[idx] = m8[b * SEQ + idx];
    } else {
        const int* m32 = (const int*)maskp;
        for (int idx = t; idx < SEQ; idx += 64) sh_mask[idx] = (unsigned char)(m32[b * SEQ + idx] != 0);
    }
    for (int idx = t; idx < NT * NT; idx += 64) sh_trans[idx] = trans[idx];
    __syncthreads();
    float sc = 0.f;
    if (t < NT) { sc = start_t[t] + sh_em[0][t]; sh_score[t] = sc; }
    __syncthreads();
    for (int s = 1; s < SEQ; ++s) {
        if (t < NT) {
            float m = -3.4e38f; int bp = 0;
            #pragma unroll
            for (int i = 0; i < NT; ++i) {
                float v = sh_score[i] + sh_trans[i * NT + t];
                if (v > m) { m = v; bp = i; }
            }
            sh_hist[s - 1][t] = (unsigned char)bp;
            float best = m + sh_em[s][t];
            if (sh_mask[s]) sc = best;
        }
        __syncthreads();
        if (t < NT) sh_score[t] = sc;
        __syncthreads();
    }
    if (t == 0) {
        float bb = -3.4e38f; int tag = 0;
        for (int j = 0; j < NT; ++j) {
            float v = sh_score[j] + end_t[j];
            if (v > bb) { bb = v; tag = j; }
        }
        for (int pos = SEQ - 1; pos >= 1; --pos) {
            sh_tags[pos] = (unsigned char)tag;
            if (sh_mask[pos]) tag = sh_hist[pos - 1][tag];
        }
        sh_tags[0] = (unsigned char)tag;
    }
    __syncthreads();
    for (int idx = t; idx < SEQ; idx += 64) {
        out[b * SEQ + idx] = sh_mask[idx] ? (int)sh_tags[idx] : 0;
    }
}

extern "C" void kernel_launch(void* const* d_in, const int* in_sizes, int n_in,
                              void* d_out, int out_size, void* d_ws, size_t ws_size,
                              hipStream_t stream) {
    const int*   ids  = (const int*)d_in[0];
    const void*  mask = d_in[1];
    const float* emb  = (const float*)d_in[2];
    const float* Wihf = (const float*)d_in[3];
    const float* Whhf = (const float*)d_in[4];
    const float* bfv  = (const float*)d_in[5];
    const float* Wihb = (const float*)d_in[6];
    const float* Whhb = (const float*)d_in[7];
    const float* bbv  = (const float*)d_in[8];
    const float* Wout = (const float*)d_in[9];
    const float* bout = (const float*)d_in[10];
    const float* st   = (const float*)d_in[11];
    const float* en   = (const float*)d_in[12];
    const float* tr   = (const float*)d_in[13];
    int* out = (int*)d_out;

    char* ws = (char*)d_ws;
    float* table = (float*)ws;                                       // 245,760,000 B
    float* emp   = (float*)(ws + 245760000);                         //   4,718,592 B
    float* hx    = (float*)(ws + 245760000 + 4718592);               //     524,288 B
    int*   tags  = (int*)(ws + 245760000 + 4718592 + 524288);        //       2,048 B
    int*   flag  = (int*)(ws + 245760000 + 4718592 + 524288 + 2048); //           4 B

    k_detect<<<1, 128, 0, stream>>>((const unsigned char*)mask, flag);
    dim3 g1(32, 469);
    k_table_gemm<<<g1, 256, 0, stream>>>(emb, Wihf, Wihb, bfv, bbv, table);
    k_lstm_cl<<<256, 512, 131072, stream>>>(ids, Whhf, Whhb, table, Wout, emp, hx, tags);
    k_viterbi<<<128, 64, 0, stream>>>(emp, bout, st, en, tr, mask, flag, out);
}